// Round 1
// baseline (676.768 us; speedup 1.0000x reference)
//
#include <hip/hip_runtime.h>
#include <hip/hip_bf16.h>

// GCN_large: per-batch-item LDS-resident bf16 MFMA pipeline.
// X [112,112] bf16 in LDS (K-padded to 128); h alternates between
// feature-major hT [feat][node] (agg B-operand) and node-major aB
// [node][feat] (proj B-operand, proj computed as h_outT = W @ aT).

#define NODE   112
#define NBATCH 4096
#define SX 136                 // Xs row stride (bf16 elems), 272B -> 4-bank shift
#define ST 136                 // hT row stride
#define SA 264                 // aB row stride, 528B -> 4-bank shift
#define XS_ELEMS (112*SX)      // 15232
#define HT_ELEMS (256*ST)      // 34816
#define AB_ELEMS (112*SA)      // 29568
#define SMEM_BYTES ((XS_ELEMS+HT_ELEMS+AB_ELEMS)*2)   // 159232 B

typedef float  f4v  __attribute__((ext_vector_type(4)));
typedef __bf16 bf8v __attribute__((ext_vector_type(8)));
typedef short  s8v  __attribute__((ext_vector_type(8)));

__device__ __forceinline__ unsigned short f2bf(float f) {
  union { float f; unsigned u; } v; v.f = f;
  unsigned r = v.u + 0x7FFFu + ((v.u >> 16) & 1u);   // RNE
  return (unsigned short)(r >> 16);
}
__device__ __forceinline__ float bf2f(unsigned short h) {
  union { unsigned u; float f; } v; v.u = ((unsigned)h) << 16; return v.f;
}
__device__ __forceinline__ bf8v ld_frag(const unsigned short* p) {
  s8v t = *(const s8v*)p;                 // 16B -> ds_read_b128 / global dwordx4
  return __builtin_bit_cast(bf8v, t);
}
#define MFMA(a,b,c) __builtin_amdgcn_mfma_f32_16x16x32_bf16((a),(b),(c),0,0,0)

// proj: dst(hT)[m=outfeat][n=node] = relu(W[m][k] * Bsrc[n][k] + bias[m])
// A from W (row-major, stride = K), B from Bsrc rows (node-major, k consec).
template<int MT, int KSTEPS>
__device__ __forceinline__ void proj_phase(
    const unsigned short* __restrict__ Wg, const float* __restrict__ bias,
    const unsigned short* Bsrc, int bstride, unsigned short* dst,
    int wave, int lane)
{
  if (wave >= MT/2) return;            // inactive waves go wait at barrier
  const int l15 = lane & 15, quad = lane >> 4;
  const int K = KSTEPS*32;
  const int mt0 = wave*2;
  f4v acc[2][7];
  #pragma unroll
  for (int i=0;i<2;i++)
    #pragma unroll
    for (int n=0;n<7;n++) acc[i][n] = (f4v){0.f,0.f,0.f,0.f};

  const unsigned short* wrow0 = Wg + (mt0*16 + l15)*K + quad*8;
  const unsigned short* wrow1 = wrow0 + 16*K;
  const unsigned short* bbase = Bsrc + l15*bstride + quad*8;
  #pragma unroll
  for (int ks=0; ks<KSTEPS; ks++) {
    bf8v a0 = ld_frag(wrow0 + ks*32);
    bf8v a1 = ld_frag(wrow1 + ks*32);
    #pragma unroll
    for (int n=0;n<7;n++) {
      bf8v bb = ld_frag(bbase + n*16*bstride + ks*32);
      acc[0][n] = MFMA(a0, bb, acc[0][n]);
      acc[1][n] = MFMA(a1, bb, acc[1][n]);
    }
  }
  #pragma unroll
  for (int i=0;i<2;i++) {
    const int mbase = (mt0+i)*16 + quad*4;
    float bi[4];
    #pragma unroll
    for (int r=0;r<4;r++) bi[r] = bias[mbase + r];
    #pragma unroll
    for (int n=0;n<7;n++)
      #pragma unroll
      for (int r=0;r<4;r++) {
        float v = acc[i][n][r] + bi[r];
        v = v > 0.f ? v : 0.f;
        dst[(mbase + r)*ST + n*16 + l15] = f2bf(v);
      }
  }
}

// agg: aB[m=node][n=feat] = X[m][k] * hT[n][k]  (K = node, padded to 128)
template<int NT>
__device__ __forceinline__ void agg_phase(
    const unsigned short* Xs_, const unsigned short* hT_, unsigned short* aB_,
    int wave, int lane)
{
  if (wave >= NT/2) return;
  const int l15 = lane & 15, quad = lane >> 4;
  const int nt0 = wave*2;
  f4v acc[7][2];
  #pragma unroll
  for (int m=0;m<7;m++) { acc[m][0] = (f4v){0,0,0,0}; acc[m][1] = (f4v){0,0,0,0}; }

  const unsigned short* xbase  = Xs_ + l15*SX + quad*8;
  const unsigned short* hbase0 = hT_ + (nt0*16 + l15)*ST + quad*8;
  const unsigned short* hbase1 = hbase0 + 16*ST;
  #pragma unroll
  for (int ks=0; ks<4; ks++) {
    bf8v b0 = ld_frag(hbase0 + ks*32);
    bf8v b1 = ld_frag(hbase1 + ks*32);
    #pragma unroll
    for (int m=0;m<7;m++) {
      bf8v a = ld_frag(xbase + m*16*SX + ks*32);
      acc[m][0] = MFMA(a, b0, acc[m][0]);
      acc[m][1] = MFMA(a, b1, acc[m][1]);
    }
  }
  #pragma unroll
  for (int m=0;m<7;m++)
    #pragma unroll
    for (int j=0;j<2;j++)
      #pragma unroll
      for (int r=0;r<4;r++)
        aB_[(m*16 + quad*4 + r)*SA + (nt0+j)*16 + l15] = f2bf(acc[m][j][r]);
}

__global__ void prep_weights(const float* __restrict__ W1, const float* __restrict__ W2,
                             const float* __restrict__ W3, const float* __restrict__ W4,
                             unsigned short* __restrict__ o)
{
  int i = blockIdx.x*256 + threadIdx.x;
  if (i < 32768) {                       // W1p [256][128], K zero-padded
    int r = i >> 7, c = i & 127;
    o[i] = (c < NODE) ? f2bf(W1[r*NODE + c]) : (unsigned short)0;
  } else if (i < 98304) {                // W2 [256][256]
    o[i] = f2bf(W2[i - 32768]);
  } else if (i < 131072) {               // W3 [128][256]
    o[i] = f2bf(W3[i - 98304]);
  } else if (i < 139264) {               // W4 [64][128]
    o[i] = f2bf(W4[i - 131072]);
  }
}

__global__ void __launch_bounds__(512) gcn_kernel(
    const float* __restrict__ x, const unsigned short* __restrict__ wsp,
    const float* __restrict__ b1, const float* __restrict__ b2,
    const float* __restrict__ b3, const float* __restrict__ b4,
    const float* __restrict__ W5, const float* __restrict__ b5,
    const float* __restrict__ Wf, const float* __restrict__ bfc,
    float* __restrict__ out)
{
  extern __shared__ unsigned short smem[];
  unsigned short* Xs = smem;
  unsigned short* hT = smem + XS_ELEMS;
  unsigned short* aB = smem + XS_ELEMS + HT_ELEMS;
  float* red = (float*)hT;               // reused for final reduction

  const int tid  = threadIdx.x;
  const int wave = tid >> 6;
  const int lane = tid & 63;

  // zero K-pad columns (cols 112..135) of Xs and hT
  for (int i = tid; i < 112*24; i += 512) { int r = i/24; Xs[r*SX + 112 + (i - r*24)] = 0; }
  for (int i = tid; i < 256*24; i += 512) { int r = i/24; hT[r*ST + 112 + (i - r*24)] = 0; }

  // stage X (fp32 global -> bf16 LDS), coalesced float4
  {
    const float4* x4 = (const float4*)(x + (size_t)blockIdx.x * (NODE*NODE));
    for (int i = tid; i < (NODE*NODE/4); i += 512) {
      float4 v = x4[i];
      int r = i / 28, c4 = (i - r*28) * 4;
      short4 pv;
      pv.x = (short)f2bf(v.x); pv.y = (short)f2bf(v.y);
      pv.z = (short)f2bf(v.z); pv.w = (short)f2bf(v.w);
      *(short4*)(Xs + r*SX + c4) = pv;   // 8B aligned -> ds_write_b64
    }
  }
  __syncthreads();

  proj_phase<16,4>(wsp,          b1, Xs, SX, hT, wave, lane);  // h1 (B = X as X^T)
  __syncthreads();
  agg_phase<16>(Xs, hT, aB, wave, lane);                       // a2
  __syncthreads();
  proj_phase<16,8>(wsp + 32768,  b2, aB, SA, hT, wave, lane);  // h2
  __syncthreads();
  agg_phase<16>(Xs, hT, aB, wave, lane);                       // a3
  __syncthreads();
  proj_phase<8,8>(wsp + 98304,   b3, aB, SA, hT, wave, lane);  // h3 (128 feat)
  __syncthreads();
  agg_phase<8>(Xs, hT, aB, wave, lane);                        // a4
  __syncthreads();
  proj_phase<4,4>(wsp + 131072,  b4, aB, SA, hT, wave, lane);  // h4 (64 feat)
  __syncthreads();
  agg_phase<4>(Xs, hT, aB, wave, lane);                        // a5 -> aB[112][64]
  __syncthreads();

  // final: h5[n] = relu(b5 + a5[n][:] . W5), out = bf + sum_n h5[n]*Wf[n]  (fp32)
  float partial = 0.f;
  if (tid < NODE) {
    const unsigned short* row = aB + tid*SA;
    float s = 0.f;
    #pragma unroll
    for (int k = 0; k < 64; k++) s += bf2f(row[k]) * W5[k];
    s += b5[0];
    s = s > 0.f ? s : 0.f;
    partial = s * Wf[tid];
  }
  red[tid] = partial;
  __syncthreads();
  if (tid == 0) {
    float s = bfc[0];
    #pragma unroll
    for (int i = 0; i < NODE; i++) s += red[i];
    out[blockIdx.x] = s;
  }
}

extern "C" void kernel_launch(void* const* d_in, const int* in_sizes, int n_in,
                              void* d_out, int out_size, void* d_ws, size_t ws_size,
                              hipStream_t stream) {
  const float* x   = (const float*)d_in[0];
  const float* W1  = (const float*)d_in[1];
  const float* b1  = (const float*)d_in[2];
  const float* W2  = (const float*)d_in[3];
  const float* b2  = (const float*)d_in[4];
  const float* W3  = (const float*)d_in[5];
  const float* b3  = (const float*)d_in[6];
  const float* W4  = (const float*)d_in[7];
  const float* b4  = (const float*)d_in[8];
  const float* W5  = (const float*)d_in[9];
  const float* b5  = (const float*)d_in[10];
  const float* Wf  = (const float*)d_in[11];
  const float* bfc = (const float*)d_in[12];
  unsigned short* wsp = (unsigned short*)d_ws;
  float* out = (float*)d_out;

  prep_weights<<<544, 256, 0, stream>>>(W1, W2, W3, W4, wsp);

  // 159232 B dynamic LDS needs the >64KB opt-in (gfx950 has 160 KiB/CU)
  (void)hipFuncSetAttribute((const void*)gcn_kernel,
                            hipFuncAttributeMaxDynamicSharedMemorySize, SMEM_BYTES);
  gcn_kernel<<<NBATCH, 512, SMEM_BYTES, stream>>>(x, wsp, b1, b2, b3, b4,
                                                  W5, b5, Wf, bfc, out);
}